// Round 12
// baseline (300.775 us; speedup 1.0000x reference)
//
#include <hip/hip_runtime.h>
#include <math.h>

#define N_NODES 512
#define NE      4096
#define H       128
#define HH      1024
#define RBFK    64
#define KCAT    576   // 128 (ai) + 384 (eij) + 64 (rbf)

typedef __attribute__((ext_vector_type(8))) short bf16x8;
typedef __attribute__((ext_vector_type(4))) float f32x4;
typedef __attribute__((ext_vector_type(4))) short short4v;

__device__ __forceinline__ short f2bf(float x) {
    unsigned u = __builtin_bit_cast(unsigned, x);
    unsigned r = u + 0x7FFFu + ((u >> 16) & 1u);   // RNE
    return (short)(r >> 16);
}
__device__ __forceinline__ float bf2f(short s) {
    return __builtin_bit_cast(float, ((unsigned)(unsigned short)s) << 16);
}

__device__ __forceinline__ void gload16(const short* g, short* l) {
    __builtin_amdgcn_global_load_lds(
        (const __attribute__((address_space(1))) void*)g,
        (__attribute__((address_space(3))) void*)l, 16, 0, 0);
}

// ---------------- sort pipeline: extract+hist+scan (1 block), then scatter ----------------

__global__ __launch_bounds__(512) void k_scan(
    const int* __restrict__ ei,
    int* __restrict__ srcG, int* __restrict__ tgtG,
    int* __restrict__ segStart, int* __restrict__ segStartT,
    int* __restrict__ cursorS, int* __restrict__ cursorT, int* __restrict__ nsegp,
    float* __restrict__ cvec)
{
    __shared__ int hS[N_NODES], hT[N_NODES], sS[N_NODES], sT[N_NODES];
    __shared__ int flag;
    int t = threadIdx.x;
    if (t == 0) {
        int any = 0;
        for (int i = 1; i < 128; i += 2) any |= ei[i];
        flag = (any == 0);
    }
    hS[t] = 0; hT[t] = 0;
    if (t < H) cvec[t] = 0.0f;
    __syncthreads();
    int is64 = flag;
    for (int e = t; e < NE; e += 512) {
        int s = is64 ? ei[2 * e]          : ei[e];
        int g = is64 ? ei[2 * NE + 2 * e] : ei[NE + e];
        srcG[e] = s; tgtG[e] = g;
        atomicAdd(&hS[s], 1);
        atomicAdd(&hT[g], 1);
    }
    __syncthreads();
    int cs = hS[t], ct = hT[t];
    sS[t] = cs; sT[t] = ct;
    __syncthreads();
    for (int off = 1; off < N_NODES; off <<= 1) {
        int a = (t >= off) ? sS[t - off] : 0;
        int b = (t >= off) ? sT[t - off] : 0;
        __syncthreads();
        sS[t] += a; sT[t] += b;
        __syncthreads();
    }
    segStart[t + 1]  = sS[t];
    segStartT[t + 1] = sT[t];
    if (t == 0) { segStart[0] = 0; segStartT[0] = 0; }
    cursorS[t] = sS[t] - cs;
    cursorT[t] = sT[t] - ct;
    hS[t] = (cs > 0) ? 1 : 0;
    __syncthreads();
    for (int off = 256; off > 0; off >>= 1) {
        if (t < off) hS[t] += hS[t + off];
        __syncthreads();
    }
    if (t == 0) nsegp[0] = hS[0];
}

__global__ void k_scatter(const int* __restrict__ src, const int* __restrict__ tgt,
                          const float* __restrict__ ew,
                          int* __restrict__ cursorS, int* __restrict__ cursorT,
                          int* __restrict__ srcS, int* __restrict__ tgtS,
                          float* __restrict__ ewS, int* __restrict__ idxT) {
    int e = blockIdx.x * blockDim.x + threadIdx.x;
    if (e < NE) {
        int s = src[e], g = tgt[e];
        int p = atomicAdd(&cursorS[s], 1);
        srcS[p] = s; tgtS[p] = g; ewS[p] = ew[e];
        int q = atomicAdd(&cursorT[g], 1);
        idxT[q] = p;
    }
}

// ---------------- fused prep ----------------
#define RA 524288      // NE*H edge features
#define RB 589824      // BcatT 576*1024
#define RBZ 65536      // BcatT zero rows 576..639
#define RQ 131072      // WqB
#define RK 131072      // WkB
#define RD 131072      // olT
#define RE 32768       // liT+ljT
#define RG 65536       // embB 512*128
#define RF 4096        // cvec partial sums (32 chunks x 128 h)
#define RTOT (RA+RB+RBZ+RQ+RK+RD+RE+RG+RF)

__global__ void k_prep_all(
    const float* __restrict__ atom_embs, const float* __restrict__ pos,
    const int* __restrict__ srcS, const int* __restrict__ tgtS, const float* __restrict__ ewS,
    const float* __restrict__ Wq, const float* __restrict__ Wk, const float* __restrict__ Wv,
    const float* __restrict__ li_w, const float* __restrict__ lj_w,
    const float* __restrict__ el_w, const float* __restrict__ rl_w,
    const float* __restrict__ ol_w, const float* __restrict__ el_b, const float* __restrict__ rl_b,
    short* __restrict__ Acat, short* __restrict__ ajB, short* __restrict__ BcatT,
    short* __restrict__ WqB, short* __restrict__ WkB, short* __restrict__ olT,
    short* __restrict__ liT, short* __restrict__ ljT, short* __restrict__ embB,
    float* __restrict__ cvec)
{
    int idx = blockIdx.x * blockDim.x + threadIdx.x;
    if (idx < RA) {
        int p = idx >> 7, h = idx & 127;
        int s = srcS[p], t = tgtS[p];
        float ew = ewS[p];
        Acat[(size_t)p * KCAT + h] = f2bf(atom_embs[t * H + h] + ew);
        ajB[idx] = f2bf(atom_embs[s * H + h] + ew);
        if (h < RBFK) {
            float dx = pos[t * 3 + 0] - pos[s * 3 + 0];
            float dy = pos[t * 3 + 1] - pos[s * 3 + 1];
            float dz = pos[t * 3 + 2] - pos[s * 3 + 2];
            float d = sqrtf(dx * dx + dy * dy + dz * dz);
            float x = d * 0.1f;
            float cut = 0.0f;
            if (x < 1.0f) {
                float x3 = x * x * x, x4 = x3 * x, x5 = x4 * x;
                cut = 1.0f - 6.0f * x5 + 15.0f * x4 - 10.0f * x3;
            }
            float ck = 1.0f + (float)h * (-0.015872295239210119f);
            float tt = expf(-d) - ck;
            Acat[(size_t)p * KCAT + 512 + h] = f2bf(cut * expf(-1024.0929857f * tt * tt));
        }
        return;
    }
    idx -= RA;
    if (idx < RB) {                       // BcatT rows: [Wv; el_w; rl_w]
        int k = idx >> 10, n = idx & 1023;
        float v = (k < 128) ? Wv[k * HH + n]
                : (k < 512) ? el_w[(k - 128) * HH + n]
                            : rl_w[(k - 512) * HH + n];
        BcatT[idx] = f2bf(v);
        return;
    }
    idx -= RB;
    if (idx < RBZ) { BcatT[RB + idx] = 0; return; }
    idx -= RBZ;
    if (idx < RQ) { WqB[idx] = f2bf(Wq[idx]); return; }
    idx -= RQ;
    if (idx < RK) { WkB[idx] = f2bf(Wk[idx]); return; }
    idx -= RK;
    if (idx < RD) {                       // olT [128 x 1024]
        int h = idx >> 10, n = idx & 1023;
        olT[idx] = f2bf(ol_w[n * H + h]);
        return;
    }
    idx -= RD;
    if (idx < RE) {                       // liT / ljT
        int which = idx >> 14, r = idx & 16383;
        int n = r >> 7, k = r & 127;
        (which ? ljT : liT)[r] = f2bf((which ? lj_w : li_w)[k * H + n]);
        return;
    }
    idx -= RE;
    if (idx < RG) { embB[idx] = f2bf(atom_embs[idx]); return; }
    idx -= RG;
    if (idx < RF) {                       // cvec partials: 32 chunks of 32 n each
        int h = idx & 127, chunk = idx >> 7;
        float acc = 0.0f;
        int n0 = chunk * 32;
        for (int n = n0; n < n0 + 32; n++)
            acc += (el_b[n] + rl_b[n]) * ol_w[n * H + h];
        atomicAdd(&cvec[h], acc);
    }
}

// ---------------- shared MFMA NT GEMM body ----------------
// out_mode: 0 = f32 (offset zoff_pitch), 1 = bf16, 3 = bf16 transposed
__device__ __forceinline__ void gemm_body(
    short* As, short* Bs,
    const short* __restrict__ A, int lda,
    const short* __restrict__ B, int ldb,
    void* __restrict__ Cp, int ldc,
    int kbeg, int kend, float alpha, const float* __restrict__ bias,
    long zoff_pitch, int out_mode, int row0, int col0)
{
    const int tid = threadIdx.x;
    const int wave = tid >> 6, lane = tid & 63;

    f32x4 acc[4][4];
#pragma unroll
    for (int i = 0; i < 4; i++)
#pragma unroll
        for (int j = 0; j < 4; j++) acc[i][j] = (f32x4){0.f, 0.f, 0.f, 0.f};

    const int m0 = (wave >> 1) * 64, n0 = (wave & 1) * 64;
    const int lr = lane >> 3;
    const int lc = (lane & 7) * 8;
    const int cl = lane & 15, quad = lane >> 4;

    for (int k0 = kbeg; k0 < kend; k0 += 64) {
#pragma unroll
        for (int i = 0; i < 4; i++) {
            int r = wave * 32 + i * 8;
            gload16(A + (size_t)(row0 + r + lr) * lda + k0 + lc, As + r * 64);
            gload16(B + (size_t)(col0 + r + lr) * ldb + k0 + lc, Bs + r * 64);
        }
        __syncthreads();
#pragma unroll
        for (int kk = 0; kk < 64; kk += 32) {
            bf16x8 af[4], bf[4];
            int ko = kk + quad * 8;
#pragma unroll
            for (int i = 0; i < 4; i++)
                af[i] = *(const bf16x8*)(As + (m0 + i * 16 + cl) * 64 + ko);
#pragma unroll
            for (int j = 0; j < 4; j++)
                bf[j] = *(const bf16x8*)(Bs + (n0 + j * 16 + cl) * 64 + ko);
#pragma unroll
            for (int i = 0; i < 4; i++)
#pragma unroll
                for (int j = 0; j < 4; j++)
                    acc[i][j] = __builtin_amdgcn_mfma_f32_16x16x32_bf16(af[i], bf[j], acc[i][j], 0, 0, 0);
        }
        __syncthreads();
    }

    if (out_mode == 1) {
        short* C = (short*)Cp;
#pragma unroll
        for (int i = 0; i < 4; i++)
#pragma unroll
            for (int j = 0; j < 4; j++) {
                int cc = col0 + n0 + j * 16 + cl;
                float bv = bias ? bias[cc] : 0.0f;
#pragma unroll
                for (int reg = 0; reg < 4; reg++) {
                    int rr = row0 + m0 + i * 16 + quad * 4 + reg;
                    C[(size_t)rr * ldc + cc] = f2bf(acc[i][j][reg] * alpha + bv);
                }
            }
    } else if (out_mode == 3) {
        short* C = (short*)Cp;
#pragma unroll
        for (int i = 0; i < 4; i++)
#pragma unroll
            for (int j = 0; j < 4; j++) {
                int cc = col0 + n0 + j * 16 + cl;
                int rr = row0 + m0 + i * 16 + quad * 4;
                short4v pack;
#pragma unroll
                for (int reg = 0; reg < 4; reg++) pack[reg] = f2bf(acc[i][j][reg] * alpha);
                *(short4v*)(C + (size_t)cc * ldc + rr) = pack;
            }
    } else {
        float* C = (float*)Cp + zoff_pitch;
#pragma unroll
        for (int i = 0; i < 4; i++)
#pragma unroll
            for (int j = 0; j < 4; j++) {
                int cc = col0 + n0 + j * 16 + cl;
#pragma unroll
                for (int reg = 0; reg < 4; reg++) {
                    int rr = row0 + m0 + i * 16 + quad * 4 + reg;
                    C[(size_t)rr * ldc + cc] = acc[i][j][reg] * alpha;
                }
            }
    }
}

__global__ __launch_bounds__(256) void k_gemm(
    const short* __restrict__ A, int lda,
    const short* __restrict__ B, int ldb,
    void* __restrict__ Cp, int ldc,
    int K, float alpha, const float* __restrict__ bias,
    long split_pitch, int out_mode)
{
    __shared__ __align__(16) short As[128 * 64];
    __shared__ __align__(16) short Bs[128 * 64];
    int kchunk = K / gridDim.z;
    gemm_body(As, Bs, A, lda, B, ldb, Cp, ldc,
              kchunk * blockIdx.z, kchunk * (blockIdx.z + 1), alpha, bias,
              (long)blockIdx.z * split_pitch, out_mode,
              blockIdx.y * 128, blockIdx.x * 128);
}

// W2T (5 blocks) + MT (1 block)
__global__ __launch_bounds__(256) void k_smallgemms(
    const short* __restrict__ olT, const short* __restrict__ BcatT,
    const short* __restrict__ WqB, const short* __restrict__ WkB,
    short* __restrict__ W2T, short* __restrict__ MT)
{
    __shared__ __align__(16) short As[128 * 64];
    __shared__ __align__(16) short Bs[128 * 64];
    if (blockIdx.x < 5) {
        gemm_body(As, Bs, olT, HH, BcatT, HH, W2T, 640, 0, HH, 1.0f, nullptr, 0, 1,
                  0, blockIdx.x * 128);
    } else {
        gemm_body(As, Bs, WqB, HH, WkB, HH, MT, 128, 0, HH, 1.0f, nullptr, 0, 3, 0, 0);
    }
}

// GT (32 blocks) + Y = emb@M (4 blocks)
__global__ __launch_bounds__(256) void k_midgemms(
    const short* __restrict__ Acat, const short* __restrict__ W2T,
    const short* __restrict__ MT, const short* __restrict__ embB,
    short* __restrict__ GT, short* __restrict__ Y)
{
    __shared__ __align__(16) short As[128 * 64];
    __shared__ __align__(16) short Bs[128 * 64];
    if (blockIdx.x < 32) {
        gemm_body(As, Bs, Acat, KCAT, W2T, 640, GT, NE, 0, KCAT, 1.0f, nullptr, 0, 3,
                  blockIdx.x * 128, 0);
    } else {
        gemm_body(As, Bs, embB, H, MT, H, Y, H, 0, H, 1.0f, nullptr, 0, 1,
                  (blockIdx.x - 32) * 128, 0);
    }
}

// Z = α·(Y @ emb^T) (16 blocks) + rank-1 vectors + colP/colB (1 block)
__global__ __launch_bounds__(256) void k_zgemm(
    const short* __restrict__ Y, const short* __restrict__ embB,
    const short* __restrict__ MT, const int* __restrict__ tgtS,
    const float* __restrict__ ewS,
    float* __restrict__ Z, float* __restrict__ pv,
    float* __restrict__ colP, float* __restrict__ colB)
{
    const float alpha = 0.08838834764831845f;
    __shared__ __align__(16) short As[128 * 64];
    __shared__ __align__(16) short Bs[128 * 64];
    if (blockIdx.x < 16) {
        gemm_body(As, Bs, Y, H, embB, H, Z, N_NODES, 0, H, alpha, nullptr, 0, 0,
                  (blockIdx.x >> 2) * 128, (blockIdx.x & 3) * 128);
    } else {
        __shared__ float csM[H];
        __shared__ float qsh[N_NODES];
        __shared__ float sSh;
        int t = threadIdx.x;
        if (t < H) {
            float a = 0.0f;
            for (int i = 0; i < H; i++) a += bf2f(MT[t * H + i]);
            csM[t] = a;
        }
        __syncthreads();
        for (int n = t; n < N_NODES; n += 256) {
            float a = 0.0f, b = 0.0f;
            for (int k = 0; k < H; k++) {
                a += bf2f(Y[n * H + k]);
                b += csM[k] * bf2f(embB[n * H + k]);
            }
            pv[n] = a; qsh[n] = b;
        }
        if (t == 0) {
            float s = 0.0f;
            for (int k = 0; k < H; k++) s += csM[k];
            sSh = s;
        }
        __syncthreads();
        float s = sSh;
        for (int c = t; c < NE; c += 256) {
            float ec = ewS[c];
            colP[c] = alpha * ec;
            colB[c] = alpha * (qsh[tgtS[c]] + ec * s);
        }
    }
}

// ---------------- fused hi/hj/eij ----------------
__global__ __launch_bounds__(256) void k_edgefeat(
    const short* __restrict__ Acat_in, const short* __restrict__ ajB,
    const short* __restrict__ liT, const short* __restrict__ ljT,
    const float* __restrict__ li_b, const float* __restrict__ lj_b,
    short* __restrict__ Acat)
{
    __shared__ __align__(16) short As[128 * 128];
    __shared__ __align__(16) short Bs[128 * 128];
    const int tid = threadIdx.x;
    const int wave = tid >> 6, lane = tid & 63;
    const int row0 = blockIdx.x * 128;
    const int cl = lane & 15, quad = lane >> 4;
    const int m0 = (wave >> 1) * 64, n0 = (wave & 1) * 64;
    const int sr = lane >> 4, sc = (lane & 15) * 8;

    f32x4 ai_acc[4][4], aj_acc[4][4];
#pragma unroll
    for (int i = 0; i < 4; i++)
#pragma unroll
        for (int j = 0; j < 4; j++) {
            ai_acc[i][j] = (f32x4){0.f, 0.f, 0.f, 0.f};
            aj_acc[i][j] = (f32x4){0.f, 0.f, 0.f, 0.f};
        }

#pragma unroll
    for (int i = 0; i < 8; i++) {
        int r = wave * 32 + i * 4;
        gload16(Acat_in + (size_t)(row0 + r + sr) * KCAT + sc, As + r * 128);
        gload16(liT + (r + sr) * 128 + sc, Bs + r * 128);
    }
    __syncthreads();
#pragma unroll
    for (int kk = 0; kk < 128; kk += 32) {
        bf16x8 af[4], bf[4];
        int ko = kk + quad * 8;
#pragma unroll
        for (int i = 0; i < 4; i++) af[i] = *(const bf16x8*)(As + (m0 + i * 16 + cl) * 128 + ko);
#pragma unroll
        for (int j = 0; j < 4; j++) bf[j] = *(const bf16x8*)(Bs + (n0 + j * 16 + cl) * 128 + ko);
#pragma unroll
        for (int i = 0; i < 4; i++)
#pragma unroll
            for (int j = 0; j < 4; j++)
                ai_acc[i][j] = __builtin_amdgcn_mfma_f32_16x16x32_bf16(af[i], bf[j], ai_acc[i][j], 0, 0, 0);
    }
    __syncthreads();
#pragma unroll
    for (int i = 0; i < 8; i++) {
        int r = wave * 32 + i * 4;
        gload16(ajB + (size_t)(row0 + r + sr) * 128 + sc, As + r * 128);
        gload16(ljT + (r + sr) * 128 + sc, Bs + r * 128);
    }
    __syncthreads();
#pragma unroll
    for (int kk = 0; kk < 128; kk += 32) {
        bf16x8 af[4], bf[4];
        int ko = kk + quad * 8;
#pragma unroll
        for (int i = 0; i < 4; i++) af[i] = *(const bf16x8*)(As + (m0 + i * 16 + cl) * 128 + ko);
#pragma unroll
        for (int j = 0; j < 4; j++) bf[j] = *(const bf16x8*)(Bs + (n0 + j * 16 + cl) * 128 + ko);
#pragma unroll
        for (int i = 0; i < 4; i++)
#pragma unroll
            for (int j = 0; j < 4; j++)
                aj_acc[i][j] = __builtin_amdgcn_mfma_f32_16x16x32_bf16(af[i], bf[j], aj_acc[i][j], 0, 0, 0);
    }
#pragma unroll
    for (int i = 0; i < 4; i++)
#pragma unroll
        for (int j = 0; j < 4; j++) {
            int cc = n0 + j * 16 + cl;
            float bi = li_b[cc], bj = lj_b[cc];
#pragma unroll
            for (int reg = 0; reg < 4; reg++) {
                int rr = row0 + m0 + i * 16 + quad * 4 + reg;
                float hv = ai_acc[i][j][reg] + bi;
                float gv = aj_acc[i][j][reg] + bj;
                short* rowp = Acat + (size_t)rr * KCAT;
                rowp[128 + cc] = f2bf(hv + gv);
                rowp[256 + cc] = f2bf(hv - gv);
                rowp[384 + cc] = f2bf(hv * gv);
            }
        }
}

// ---------------- Pagg: per-tgt-node aggregated softmax rows ----------------
// block n: Pagg[n,c] = sum_{e: tgt_e = n} exp(l[e,c]) * rDen_e[src_c]
// l[e,c] = Z[n,tc_c] + colP[c]*pv[n] + ew_e*colB[c]   (Z pre-scaled by alpha)
__global__ __launch_bounds__(256) void k_pagg(
    const float* __restrict__ Z, const float* __restrict__ pv,
    const float* __restrict__ colP, const float* __restrict__ colB,
    const int* __restrict__ tgtS, const float* __restrict__ ewS,
    const int* __restrict__ srcS, const int* __restrict__ segStart,
    const int* __restrict__ segStartT, const int* __restrict__ idxT,
    short* __restrict__ PaggB)
{
    __shared__ float zrow[N_NODES];   // 2 KB
    __shared__ float Pacc[NE];        // 16 KB
    __shared__ float row[NE];         // 16 KB
    __shared__ float rDe[N_NODES];    // 2 KB
    const int n = blockIdx.x, t = threadIdx.x;
    for (int i = t; i < N_NODES; i += 256)
        zrow[i] = Z[(size_t)n * N_NODES + i];
    for (int c = t; c < NE; c += 256) Pacc[c] = 0.0f;
    __syncthreads();
    const float p_n = pv[n];
    const int a = segStartT[n], b = segStartT[n + 1];
    for (int ei = a; ei < b; ei++) {
        const int e = idxT[ei];
        const float er = ewS[e];
        for (int c = t; c < NE; c += 256)
            row[c] = __expf(zrow[tgtS[c]] + colP[c] * p_n + er * colB[c]);
        __syncthreads();
        for (int s = t; s < N_NODES; s += 256) {
            int sa = segStart[s], sb = segStart[s + 1];
            float sum = 0.0f;
            for (int p = sa; p < sb; p++) sum += row[p];
            rDe[s] = (sum > 0.0f) ? 1.0f / sum : 0.0f;
        }
        __syncthreads();
        for (int c = t; c < NE; c += 256)
            Pacc[c] += row[c] * rDe[srcS[c]];
        __syncthreads();
    }
    short* pr = PaggB + (size_t)n * NE;
    for (int c = 2 * t; c < NE; c += 512) {
        unsigned lo = (unsigned short)f2bf(Pacc[c]);
        unsigned hi = (unsigned short)f2bf(Pacc[c + 1]);
        *(unsigned*)(pr + c) = lo | (hi << 16);
    }
}

// ---------------- head: sum 8 agg partials + LN + FFN + LN ----------------
__global__ __launch_bounds__(128) void k_head(
    const float* __restrict__ aggP, const int* __restrict__ segStartT,
    const int* __restrict__ nsegp,
    const float* __restrict__ cvec, const float* __restrict__ ol_b,
    const float* __restrict__ ln_g, const float* __restrict__ ln_b,
    const float* __restrict__ f1_w, const float* __restrict__ f1_b,
    const float* __restrict__ f2_w, const float* __restrict__ f2_b,
    const float* __restrict__ f3_w, const float* __restrict__ f3_b,
    float* __restrict__ out)
{
    __shared__ float x[H];
    __shared__ float red[H];
    int t = threadIdx.x, row = blockIdx.x;
    int cnt = segStartT[row + 1] - segStartT[row];
    float v = (float)cnt * (ol_b[t] + (float)nsegp[0] * cvec[t]);
    const float* ap = aggP + (size_t)row * H + t;
#pragma unroll
    for (int z = 0; z < 8; z++) v += ap[(size_t)z * N_NODES * H];
    red[t] = v; __syncthreads();
    for (int s = 64; s > 0; s >>= 1) { if (t < s) red[t] += red[t + s]; __syncthreads(); }
    float mu = red[0] * (1.0f / H); __syncthreads();
    float dv = v - mu;
    red[t] = dv * dv; __syncthreads();
    for (int s = 64; s > 0; s >>= 1) { if (t < s) red[t] += red[t + s]; __syncthreads(); }
    float var = red[0] * (1.0f / H); __syncthreads();
    x[t] = dv * rsqrtf(var + 1e-5f) * ln_g[t] + ln_b[t];
    __syncthreads();
    const float* Ws[3] = { f1_w, f2_w, f3_w };
    const float* Bb[3] = { f1_b, f2_b, f3_b };
    for (int l = 0; l < 3; l++) {
        float acc = Bb[l][t];
        const float* Wl = Ws[l];
        for (int k = 0; k < H; k++) acc = fmaf(x[k], Wl[k * H + t], acc);
        float o = fmaxf(acc, 0.0f) + log1pf(expf(-fabsf(acc)));
        __syncthreads();
        x[t] = o;
        __syncthreads();
    }
    float xv = x[t];
    red[t] = xv; __syncthreads();
    for (int s = 64; s > 0; s >>= 1) { if (t < s) red[t] += red[t + s]; __syncthreads(); }
    mu = red[0] * (1.0f / H); __syncthreads();
    float dv2 = xv - mu;
    red[t] = dv2 * dv2; __syncthreads();
    for (int s = 64; s > 0; s >>= 1) { if (t < s) red[t] += red[t + s]; __syncthreads(); }
    var = red[0] * (1.0f / H);
    out[row * H + t] = dv2 * rsqrtf(var + 1e-5f) * ln_g[t] + ln_b[t];
}

// ---------------- launch ----------------

extern "C" void kernel_launch(void* const* d_in, const int* in_sizes, int n_in,
                              void* d_out, int out_size, void* d_ws, size_t ws_size,
                              hipStream_t stream) {
    const float* atom_embs   = (const float*)d_in[0];
    const float* pos         = (const float*)d_in[1];
    const float* edge_weight = (const float*)d_in[2];
    const int*   edge_idx    = (const int*)d_in[3];
    const float* Wq   = (const float*)d_in[4];
    const float* Wk   = (const float*)d_in[5];
    const float* Wv   = (const float*)d_in[6];
    const float* li_w = (const float*)d_in[7];
    const float* li_b = (const float*)d_in[8];
    const float* lj_w = (const float*)d_in[9];
    const float* lj_b = (const float*)d_in[10];
    const float* el_w = (const float*)d_in[11];
    const float* el_b = (const float*)d_in[12];
    const float* rl_w = (const float*)d_in[13];
    const float* rl_b = (const float*)d_in[14];
    const float* ol_w = (const float*)d_in[15];
    const float* ol_b = (const float*)d_in[16];
    const float* ln_g = (const float*)d_in[17];
    const float* ln_b = (const float*)d_in[18];
    const float* f1_w = (const float*)d_in[19];
    const float* f1_b = (const float*)d_in[20];
    const float* f2_w = (const float*)d_in[21];
    const float* f2_b = (const float*)d_in[22];
    const float* f3_w = (const float*)d_in[23];
    const float* f3_b = (const float*)d_in[24];
    float* out = (float*)d_out;

    char* w = (char*)d_ws;
    size_t off = 0;
    auto alloc = [&](size_t bytes) -> void* {
        void* p = w + off;
        off += (bytes + 255) & ~(size_t)255;
        return p;
    };
    int*   src       = (int*)alloc(NE * 4);
    int*   tgt       = (int*)alloc(NE * 4);
    int*   srcS      = (int*)alloc(NE * 4);
    int*   tgtS      = (int*)alloc(NE * 4);
    float* ewS       = (float*)alloc(NE * 4);
    int*   segStart  = (int*)alloc((N_NODES + 1) * 4);
    int*   segStartT = (int*)alloc((N_NODES + 1) * 4);
    int*   cursorS   = (int*)alloc(N_NODES * 4);
    int*   cursorT   = (int*)alloc(N_NODES * 4);
    int*   idxT      = (int*)alloc(NE * 4);
    int*   nsegp     = (int*)alloc(4);
    short* Acat   = (short*)alloc((size_t)NE * KCAT * 2);
    short* ajB    = (short*)alloc((size_t)NE * H * 2);
    short* BcatT  = (short*)alloc((size_t)640 * HH * 2);
    short* WqB    = (short*)alloc((size_t)H * HH * 2);
    short* WkB    = (short*)alloc((size_t)H * HH * 2);
    short* olT    = (short*)alloc((size_t)H * HH * 2);
    short* liT    = (short*)alloc((size_t)H * H * 2);
    short* ljT    = (short*)alloc((size_t)H * H * 2);
    short* embB   = (short*)alloc((size_t)N_NODES * H * 2);
    float* cvec   = (float*)alloc(H * 4);
    short* W2T    = (short*)alloc((size_t)H * 640 * 2);
    short* MT     = (short*)alloc((size_t)H * H * 2);
    short* Y      = (short*)alloc((size_t)N_NODES * H * 2);
    float* Z      = (float*)alloc((size_t)N_NODES * N_NODES * 4);
    float* pv     = (float*)alloc(N_NODES * 4);
    float* colP   = (float*)alloc(NE * 4);
    float* colB   = (float*)alloc(NE * 4);
    short* GT     = (short*)alloc((size_t)H * NE * 2);
    short* PaggB  = (short*)alloc((size_t)N_NODES * NE * 2);
    float* aggP   = (float*)alloc((size_t)8 * N_NODES * H * 4);

    k_scan<<<1, 512, 0, stream>>>(edge_idx, src, tgt, segStart, segStartT,
                                  cursorS, cursorT, nsegp, cvec);
    k_scatter<<<NE / 256, 256, 0, stream>>>(src, tgt, edge_weight, cursorS, cursorT,
                                            srcS, tgtS, ewS, idxT);
    k_prep_all<<<(RTOT + 255) / 256, 256, 0, stream>>>(
        atom_embs, pos, srcS, tgtS, ewS,
        Wq, Wk, Wv, li_w, lj_w, el_w, rl_w, ol_w, el_b, rl_b,
        Acat, ajB, BcatT, WqB, WkB, olT, liT, ljT, embB, cvec);
    k_edgefeat<<<NE / 128, 256, 0, stream>>>(Acat, ajB, liT, ljT, li_b, lj_b, Acat);

    k_smallgemms<<<6, 256, 0, stream>>>(olT, BcatT, WqB, WkB, W2T, MT);
    k_midgemms<<<36, 256, 0, stream>>>(Acat, W2T, MT, embB, GT, Y);
    k_zgemm<<<17, 256, 0, stream>>>(Y, embB, MT, tgtS, ewS, Z, pv, colP, colB);

    // Pagg: 512 blocks (one per tgt node)
    k_pagg<<<N_NODES, 256, 0, stream>>>(Z, pv, colP, colB, tgtS, ewS, srcS,
                                        segStart, segStartT, idxT, PaggB);
    // agg = Pagg @ G : [512 x 128], K=4096 split-K=8 -> aggP partials
    {
        dim3 g(1, N_NODES / 128, 8);
        k_gemm<<<g, 256, 0, stream>>>(PaggB, NE, GT, NE, aggP, H, NE, 1.0f, nullptr,
                                      (long)N_NODES * H, 0);
    }
    k_head<<<N_NODES, 128, 0, stream>>>(aggP, segStartT, nsegp, cvec, ol_b,
                                        ln_g, ln_b, f1_w, f1_b, f2_w, f2_b, f3_w, f3_b, out);
}

// Round 13
// 241.445 us; speedup vs baseline: 1.2457x; 1.2457x over previous
//
#include <hip/hip_runtime.h>
#include <math.h>

#define N_NODES 512
#define NE      4096
#define H       128
#define HH      1024
#define RBFK    64
#define KCAT    576   // 128 (ai) + 384 (eij) + 64 (rbf)

typedef __attribute__((ext_vector_type(8))) short bf16x8;
typedef __attribute__((ext_vector_type(4))) float f32x4;
typedef __attribute__((ext_vector_type(4))) short short4v;

__device__ __forceinline__ short f2bf(float x) {
    unsigned u = __builtin_bit_cast(unsigned, x);
    unsigned r = u + 0x7FFFu + ((u >> 16) & 1u);   // RNE
    return (short)(r >> 16);
}
__device__ __forceinline__ float bf2f(short s) {
    return __builtin_bit_cast(float, ((unsigned)(unsigned short)s) << 16);
}

__device__ __forceinline__ void gload16(const short* g, short* l) {
    __builtin_amdgcn_global_load_lds(
        (const __attribute__((address_space(1))) void*)g,
        (__attribute__((address_space(3))) void*)l, 16, 0, 0);
}

// ---------------- sort pipeline: extract+hist+scan (1 block), then scatter ----------------

__global__ __launch_bounds__(512) void k_scan(
    const int* __restrict__ ei,
    int* __restrict__ srcG, int* __restrict__ tgtG,
    int* __restrict__ segStart, int* __restrict__ segStartT,
    int* __restrict__ cursorS, int* __restrict__ cursorT, int* __restrict__ nsegp,
    float* __restrict__ cvec)
{
    __shared__ int hS[N_NODES], hT[N_NODES], sS[N_NODES], sT[N_NODES];
    __shared__ int flag;
    int t = threadIdx.x;
    if (t == 0) {
        int any = 0;
        for (int i = 1; i < 128; i += 2) any |= ei[i];
        flag = (any == 0);
    }
    hS[t] = 0; hT[t] = 0;
    if (t < H) cvec[t] = 0.0f;
    __syncthreads();
    int is64 = flag;
    for (int e = t; e < NE; e += 512) {
        int s = is64 ? ei[2 * e]          : ei[e];
        int g = is64 ? ei[2 * NE + 2 * e] : ei[NE + e];
        srcG[e] = s; tgtG[e] = g;
        atomicAdd(&hS[s], 1);
        atomicAdd(&hT[g], 1);
    }
    __syncthreads();
    int cs = hS[t], ct = hT[t];
    sS[t] = cs; sT[t] = ct;
    __syncthreads();
    for (int off = 1; off < N_NODES; off <<= 1) {
        int a = (t >= off) ? sS[t - off] : 0;
        int b = (t >= off) ? sT[t - off] : 0;
        __syncthreads();
        sS[t] += a; sT[t] += b;
        __syncthreads();
    }
    segStart[t + 1]  = sS[t];
    segStartT[t + 1] = sT[t];
    if (t == 0) { segStart[0] = 0; segStartT[0] = 0; }
    cursorS[t] = sS[t] - cs;
    cursorT[t] = sT[t] - ct;
    hS[t] = (cs > 0) ? 1 : 0;
    __syncthreads();
    for (int off = 256; off > 0; off >>= 1) {
        if (t < off) hS[t] += hS[t + off];
        __syncthreads();
    }
    if (t == 0) nsegp[0] = hS[0];
}

__global__ void k_scatter(const int* __restrict__ src, const int* __restrict__ tgt,
                          const float* __restrict__ ew,
                          int* __restrict__ cursorS, int* __restrict__ cursorT,
                          int* __restrict__ srcS, int* __restrict__ tgtS,
                          float* __restrict__ ewS, int* __restrict__ idxT) {
    int e = blockIdx.x * blockDim.x + threadIdx.x;
    if (e < NE) {
        int s = src[e], g = tgt[e];
        int p = atomicAdd(&cursorS[s], 1);
        srcS[p] = s; tgtS[p] = g; ewS[p] = ew[e];
        int q = atomicAdd(&cursorT[g], 1);
        idxT[q] = p;
    }
}

// ---------------- fused prep ----------------
#define RA 524288      // NE*H edge features
#define RB 589824      // BcatT 576*1024
#define RBZ 65536      // BcatT zero rows 576..639
#define RQ 131072      // WqB
#define RK 131072      // WkB
#define RD 131072      // olT
#define RE 32768       // liT+ljT
#define RG 65536       // embB 512*128
#define RF 4096        // cvec partial sums (32 chunks x 128 h)
#define RTOT (RA+RB+RBZ+RQ+RK+RD+RE+RG+RF)

__global__ void k_prep_all(
    const float* __restrict__ atom_embs, const float* __restrict__ pos,
    const int* __restrict__ srcS, const int* __restrict__ tgtS, const float* __restrict__ ewS,
    const float* __restrict__ Wq, const float* __restrict__ Wk, const float* __restrict__ Wv,
    const float* __restrict__ li_w, const float* __restrict__ lj_w,
    const float* __restrict__ el_w, const float* __restrict__ rl_w,
    const float* __restrict__ ol_w, const float* __restrict__ el_b, const float* __restrict__ rl_b,
    short* __restrict__ Acat, short* __restrict__ ajB, short* __restrict__ BcatT,
    short* __restrict__ WqB, short* __restrict__ WkB, short* __restrict__ olT,
    short* __restrict__ liT, short* __restrict__ ljT, short* __restrict__ embB,
    float* __restrict__ cvec)
{
    int idx = blockIdx.x * blockDim.x + threadIdx.x;
    if (idx < RA) {
        int p = idx >> 7, h = idx & 127;
        int s = srcS[p], t = tgtS[p];
        float ew = ewS[p];
        Acat[(size_t)p * KCAT + h] = f2bf(atom_embs[t * H + h] + ew);
        ajB[idx] = f2bf(atom_embs[s * H + h] + ew);
        if (h < RBFK) {
            float dx = pos[t * 3 + 0] - pos[s * 3 + 0];
            float dy = pos[t * 3 + 1] - pos[s * 3 + 1];
            float dz = pos[t * 3 + 2] - pos[s * 3 + 2];
            float d = sqrtf(dx * dx + dy * dy + dz * dz);
            float x = d * 0.1f;
            float cut = 0.0f;
            if (x < 1.0f) {
                float x3 = x * x * x, x4 = x3 * x, x5 = x4 * x;
                cut = 1.0f - 6.0f * x5 + 15.0f * x4 - 10.0f * x3;
            }
            float ck = 1.0f + (float)h * (-0.015872295239210119f);
            float tt = expf(-d) - ck;
            Acat[(size_t)p * KCAT + 512 + h] = f2bf(cut * expf(-1024.0929857f * tt * tt));
        }
        return;
    }
    idx -= RA;
    if (idx < RB) {                       // BcatT rows: [Wv; el_w; rl_w]
        int k = idx >> 10, n = idx & 1023;
        float v = (k < 128) ? Wv[k * HH + n]
                : (k < 512) ? el_w[(k - 128) * HH + n]
                            : rl_w[(k - 512) * HH + n];
        BcatT[idx] = f2bf(v);
        return;
    }
    idx -= RB;
    if (idx < RBZ) { BcatT[RB + idx] = 0; return; }
    idx -= RBZ;
    if (idx < RQ) { WqB[idx] = f2bf(Wq[idx]); return; }
    idx -= RQ;
    if (idx < RK) { WkB[idx] = f2bf(Wk[idx]); return; }
    idx -= RK;
    if (idx < RD) {                       // olT [128 x 1024]
        int h = idx >> 10, n = idx & 1023;
        olT[idx] = f2bf(ol_w[n * H + h]);
        return;
    }
    idx -= RD;
    if (idx < RE) {                       // liT / ljT
        int which = idx >> 14, r = idx & 16383;
        int n = r >> 7, k = r & 127;
        (which ? ljT : liT)[r] = f2bf((which ? lj_w : li_w)[k * H + n]);
        return;
    }
    idx -= RE;
    if (idx < RG) { embB[idx] = f2bf(atom_embs[idx]); return; }
    idx -= RG;
    if (idx < RF) {                       // cvec partials: 32 chunks of 32 n each
        int h = idx & 127, chunk = idx >> 7;
        float acc = 0.0f;
        int n0 = chunk * 32;
        for (int n = n0; n < n0 + 32; n++)
            acc += (el_b[n] + rl_b[n]) * ol_w[n * H + h];
        atomicAdd(&cvec[h], acc);
    }
}

// ---------------- shared MFMA NT GEMM body ----------------
// out_mode: 0 = f32 (offset zoff_pitch), 1 = bf16, 3 = bf16 transposed
__device__ __forceinline__ void gemm_body(
    short* As, short* Bs,
    const short* __restrict__ A, int lda,
    const short* __restrict__ B, int ldb,
    void* __restrict__ Cp, int ldc,
    int kbeg, int kend, float alpha, const float* __restrict__ bias,
    long zoff_pitch, int out_mode, int row0, int col0)
{
    const int tid = threadIdx.x;
    const int wave = tid >> 6, lane = tid & 63;

    f32x4 acc[4][4];
#pragma unroll
    for (int i = 0; i < 4; i++)
#pragma unroll
        for (int j = 0; j < 4; j++) acc[i][j] = (f32x4){0.f, 0.f, 0.f, 0.f};

    const int m0 = (wave >> 1) * 64, n0 = (wave & 1) * 64;
    const int lr = lane >> 3;
    const int lc = (lane & 7) * 8;
    const int cl = lane & 15, quad = lane >> 4;

    for (int k0 = kbeg; k0 < kend; k0 += 64) {
#pragma unroll
        for (int i = 0; i < 4; i++) {
            int r = wave * 32 + i * 8;
            gload16(A + (size_t)(row0 + r + lr) * lda + k0 + lc, As + r * 64);
            gload16(B + (size_t)(col0 + r + lr) * ldb + k0 + lc, Bs + r * 64);
        }
        __syncthreads();
#pragma unroll
        for (int kk = 0; kk < 64; kk += 32) {
            bf16x8 af[4], bf[4];
            int ko = kk + quad * 8;
#pragma unroll
            for (int i = 0; i < 4; i++)
                af[i] = *(const bf16x8*)(As + (m0 + i * 16 + cl) * 64 + ko);
#pragma unroll
            for (int j = 0; j < 4; j++)
                bf[j] = *(const bf16x8*)(Bs + (n0 + j * 16 + cl) * 64 + ko);
#pragma unroll
            for (int i = 0; i < 4; i++)
#pragma unroll
                for (int j = 0; j < 4; j++)
                    acc[i][j] = __builtin_amdgcn_mfma_f32_16x16x32_bf16(af[i], bf[j], acc[i][j], 0, 0, 0);
        }
        __syncthreads();
    }

    if (out_mode == 1) {
        short* C = (short*)Cp;
#pragma unroll
        for (int i = 0; i < 4; i++)
#pragma unroll
            for (int j = 0; j < 4; j++) {
                int cc = col0 + n0 + j * 16 + cl;
                float bv = bias ? bias[cc] : 0.0f;
#pragma unroll
                for (int reg = 0; reg < 4; reg++) {
                    int rr = row0 + m0 + i * 16 + quad * 4 + reg;
                    C[(size_t)rr * ldc + cc] = f2bf(acc[i][j][reg] * alpha + bv);
                }
            }
    } else if (out_mode == 3) {
        short* C = (short*)Cp;
#pragma unroll
        for (int i = 0; i < 4; i++)
#pragma unroll
            for (int j = 0; j < 4; j++) {
                int cc = col0 + n0 + j * 16 + cl;
                int rr = row0 + m0 + i * 16 + quad * 4;
                short4v pack;
#pragma unroll
                for (int reg = 0; reg < 4; reg++) pack[reg] = f2bf(acc[i][j][reg] * alpha);
                *(short4v*)(C + (size_t)cc * ldc + rr) = pack;
            }
    } else {
        float* C = (float*)Cp + zoff_pitch;
#pragma unroll
        for (int i = 0; i < 4; i++)
#pragma unroll
            for (int j = 0; j < 4; j++) {
                int cc = col0 + n0 + j * 16 + cl;
#pragma unroll
                for (int reg = 0; reg < 4; reg++) {
                    int rr = row0 + m0 + i * 16 + quad * 4 + reg;
                    C[(size_t)rr * ldc + cc] = acc[i][j][reg] * alpha;
                }
            }
    }
}

__global__ __launch_bounds__(256) void k_gemm(
    const short* __restrict__ A, int lda,
    const short* __restrict__ B, int ldb,
    void* __restrict__ Cp, int ldc,
    int K, float alpha, const float* __restrict__ bias,
    long split_pitch, int out_mode)
{
    __shared__ __align__(16) short As[128 * 64];
    __shared__ __align__(16) short Bs[128 * 64];
    int kchunk = K / gridDim.z;
    gemm_body(As, Bs, A, lda, B, ldb, Cp, ldc,
              kchunk * blockIdx.z, kchunk * (blockIdx.z + 1), alpha, bias,
              (long)blockIdx.z * split_pitch, out_mode,
              blockIdx.y * 128, blockIdx.x * 128);
}

// W2T (5 blocks) + MT (1 block)
__global__ __launch_bounds__(256) void k_smallgemms(
    const short* __restrict__ olT, const short* __restrict__ BcatT,
    const short* __restrict__ WqB, const short* __restrict__ WkB,
    short* __restrict__ W2T, short* __restrict__ MT)
{
    __shared__ __align__(16) short As[128 * 64];
    __shared__ __align__(16) short Bs[128 * 64];
    if (blockIdx.x < 5) {
        gemm_body(As, Bs, olT, HH, BcatT, HH, W2T, 640, 0, HH, 1.0f, nullptr, 0, 1,
                  0, blockIdx.x * 128);
    } else {
        gemm_body(As, Bs, WqB, HH, WkB, HH, MT, 128, 0, HH, 1.0f, nullptr, 0, 3, 0, 0);
    }
}

// GT (32 blocks) + Y = emb@M (4 blocks)
__global__ __launch_bounds__(256) void k_midgemms(
    const short* __restrict__ Acat, const short* __restrict__ W2T,
    const short* __restrict__ MT, const short* __restrict__ embB,
    short* __restrict__ GT, short* __restrict__ Y)
{
    __shared__ __align__(16) short As[128 * 64];
    __shared__ __align__(16) short Bs[128 * 64];
    if (blockIdx.x < 32) {
        gemm_body(As, Bs, Acat, KCAT, W2T, 640, GT, NE, 0, KCAT, 1.0f, nullptr, 0, 3,
                  blockIdx.x * 128, 0);
    } else {
        gemm_body(As, Bs, embB, H, MT, H, Y, H, 0, H, 1.0f, nullptr, 0, 1,
                  (blockIdx.x - 32) * 128, 0);
    }
}

// Z = α·(Y @ emb^T) (16 blocks) + rank-1 vectors + colP/colB (1 block)
__global__ __launch_bounds__(256) void k_zgemm(
    const short* __restrict__ Y, const short* __restrict__ embB,
    const short* __restrict__ MT, const int* __restrict__ tgtS,
    const float* __restrict__ ewS,
    float* __restrict__ Z, float* __restrict__ pv,
    float* __restrict__ colP, float* __restrict__ colB)
{
    const float alpha = 0.08838834764831845f;
    __shared__ __align__(16) short As[128 * 64];
    __shared__ __align__(16) short Bs[128 * 64];
    if (blockIdx.x < 16) {
        gemm_body(As, Bs, Y, H, embB, H, Z, N_NODES, 0, H, alpha, nullptr, 0, 0,
                  (blockIdx.x >> 2) * 128, (blockIdx.x & 3) * 128);
    } else {
        __shared__ float csM[H];
        __shared__ float qsh[N_NODES];
        __shared__ float sSh;
        int t = threadIdx.x;
        if (t < H) {
            float a = 0.0f;
            for (int i = 0; i < H; i++) a += bf2f(MT[t * H + i]);
            csM[t] = a;
        }
        __syncthreads();
        for (int n = t; n < N_NODES; n += 256) {
            float a = 0.0f, b = 0.0f;
            for (int k = 0; k < H; k++) {
                a += bf2f(Y[n * H + k]);
                b += csM[k] * bf2f(embB[n * H + k]);
            }
            pv[n] = a; qsh[n] = b;
        }
        if (t == 0) {
            float s = 0.0f;
            for (int k = 0; k < H; k++) s += csM[k];
            sSh = s;
        }
        __syncthreads();
        float s = sSh;
        for (int c = t; c < NE; c += 256) {
            float ec = ewS[c];
            colP[c] = alpha * ec;
            colB[c] = alpha * (qsh[tgtS[c]] + ec * s);
        }
    }
}

// ---------------- fused hi/hj/eij ----------------
__global__ __launch_bounds__(256) void k_edgefeat(
    const short* __restrict__ Acat_in, const short* __restrict__ ajB,
    const short* __restrict__ liT, const short* __restrict__ ljT,
    const float* __restrict__ li_b, const float* __restrict__ lj_b,
    short* __restrict__ Acat)
{
    __shared__ __align__(16) short As[128 * 128];
    __shared__ __align__(16) short Bs[128 * 128];
    const int tid = threadIdx.x;
    const int wave = tid >> 6, lane = tid & 63;
    const int row0 = blockIdx.x * 128;
    const int cl = lane & 15, quad = lane >> 4;
    const int m0 = (wave >> 1) * 64, n0 = (wave & 1) * 64;
    const int sr = lane >> 4, sc = (lane & 15) * 8;

    f32x4 ai_acc[4][4], aj_acc[4][4];
#pragma unroll
    for (int i = 0; i < 4; i++)
#pragma unroll
        for (int j = 0; j < 4; j++) {
            ai_acc[i][j] = (f32x4){0.f, 0.f, 0.f, 0.f};
            aj_acc[i][j] = (f32x4){0.f, 0.f, 0.f, 0.f};
        }

#pragma unroll
    for (int i = 0; i < 8; i++) {
        int r = wave * 32 + i * 4;
        gload16(Acat_in + (size_t)(row0 + r + sr) * KCAT + sc, As + r * 128);
        gload16(liT + (r + sr) * 128 + sc, Bs + r * 128);
    }
    __syncthreads();
#pragma unroll
    for (int kk = 0; kk < 128; kk += 32) {
        bf16x8 af[4], bf[4];
        int ko = kk + quad * 8;
#pragma unroll
        for (int i = 0; i < 4; i++) af[i] = *(const bf16x8*)(As + (m0 + i * 16 + cl) * 128 + ko);
#pragma unroll
        for (int j = 0; j < 4; j++) bf[j] = *(const bf16x8*)(Bs + (n0 + j * 16 + cl) * 128 + ko);
#pragma unroll
        for (int i = 0; i < 4; i++)
#pragma unroll
            for (int j = 0; j < 4; j++)
                ai_acc[i][j] = __builtin_amdgcn_mfma_f32_16x16x32_bf16(af[i], bf[j], ai_acc[i][j], 0, 0, 0);
    }
    __syncthreads();
#pragma unroll
    for (int i = 0; i < 8; i++) {
        int r = wave * 32 + i * 4;
        gload16(ajB + (size_t)(row0 + r + sr) * 128 + sc, As + r * 128);
        gload16(ljT + (r + sr) * 128 + sc, Bs + r * 128);
    }
    __syncthreads();
#pragma unroll
    for (int kk = 0; kk < 128; kk += 32) {
        bf16x8 af[4], bf[4];
        int ko = kk + quad * 8;
#pragma unroll
        for (int i = 0; i < 4; i++) af[i] = *(const bf16x8*)(As + (m0 + i * 16 + cl) * 128 + ko);
#pragma unroll
        for (int j = 0; j < 4; j++) bf[j] = *(const bf16x8*)(Bs + (n0 + j * 16 + cl) * 128 + ko);
#pragma unroll
        for (int i = 0; i < 4; i++)
#pragma unroll
            for (int j = 0; j < 4; j++)
                aj_acc[i][j] = __builtin_amdgcn_mfma_f32_16x16x32_bf16(af[i], bf[j], aj_acc[i][j], 0, 0, 0);
    }
#pragma unroll
    for (int i = 0; i < 4; i++)
#pragma unroll
        for (int j = 0; j < 4; j++) {
            int cc = n0 + j * 16 + cl;
            float bi = li_b[cc], bj = lj_b[cc];
#pragma unroll
            for (int reg = 0; reg < 4; reg++) {
                int rr = row0 + m0 + i * 16 + quad * 4 + reg;
                float hv = ai_acc[i][j][reg] + bi;
                float gv = aj_acc[i][j][reg] + bj;
                short* rowp = Acat + (size_t)rr * KCAT;
                rowp[128 + cc] = f2bf(hv + gv);
                rowp[256 + cc] = f2bf(hv - gv);
                rowp[384 + cc] = f2bf(hv * gv);
            }
        }
}

// ---------------- denominators (max-free): rDen[e][n] = 1/sum_{c in seg n} exp(l[e,c]) ----------------
__global__ __launch_bounds__(512) void k_denom(
    const float* __restrict__ Z, const float* __restrict__ pv,
    const float* __restrict__ colP, const float* __restrict__ colB,
    const int* __restrict__ tgtS, const float* __restrict__ ewS,
    const int* __restrict__ segStart, float* __restrict__ rDen)
{
    __shared__ float row[NE];        // 16 KB
    __shared__ float zrow[N_NODES];  // 2 KB
    const int r = blockIdx.x, t = threadIdx.x;
    const int tr = tgtS[r];
    const float er = ewS[r];
    for (int i = t; i < N_NODES; i += 512)
        zrow[i] = Z[(size_t)tr * N_NODES + i];
    __syncthreads();
    const float p_tr = pv[tr];
    for (int c = t; c < NE; c += 512)
        row[c] = __expf(zrow[tgtS[c]] + colP[c] * p_tr + er * colB[c]);
    __syncthreads();
    float* rd = rDen + (size_t)r * N_NODES;
    if (t < N_NODES) {
        int a = segStart[t], b = segStart[t + 1];
        float s = 0.0f;
        for (int p = a; p < b; p++) s += row[p];
        rd[t] = (s > 0.0f) ? 1.0f / s : 0.0f;
    }
}

// ---------------- Pagg (barrier-free): Pagg[n,c] = sum_{e:tgt=n} exp(l[e,c])*rDen[e][src_c] ----------------
// grid (4 col-chunks, 512 nodes); 256 threads; 4 cols/thread.
__global__ __launch_bounds__(256) void k_pagg2(
    const float* __restrict__ Z, const float* __restrict__ pv,
    const float* __restrict__ colP, const float* __restrict__ colB,
    const float* __restrict__ rDen,
    const int* __restrict__ tgtS, const float* __restrict__ ewS,
    const int* __restrict__ srcS, const int* __restrict__ segStartT,
    const int* __restrict__ idxT, short* __restrict__ PaggB)
{
    __shared__ float zrow[N_NODES];   // 2 KB
    __shared__ float erL[32];
    __shared__ int   eL[32];
    const int n = blockIdx.y;
    const int c0 = blockIdx.x * 1024;
    const int t = threadIdx.x;
    for (int i = t; i < N_NODES; i += 256)
        zrow[i] = Z[(size_t)n * N_NODES + i];
    __syncthreads();
    const float p_n = pv[n];
    float A4[4], cB4[4];
    int sc4[4];
#pragma unroll
    for (int q = 0; q < 4; q++) {
        int c = c0 + t + q * 256;
        A4[q]  = zrow[tgtS[c]] + colP[c] * p_n;
        cB4[q] = colB[c];
        sc4[q] = srcS[c];
    }
    float acc[4] = {0.f, 0.f, 0.f, 0.f};
    const int a = segStartT[n], b = segStartT[n + 1];
    for (int ch = a; ch < b; ch += 32) {
        int ne = b - ch; if (ne > 32) ne = 32;
        __syncthreads();
        if (t < ne) { int e = idxT[ch + t]; eL[t] = e; erL[t] = ewS[e]; }
        __syncthreads();
        for (int k = 0; k < ne; k++) {
            const float er = erL[k];
            const float* rde = rDen + (size_t)eL[k] * N_NODES;
#pragma unroll
            for (int q = 0; q < 4; q++)
                acc[q] += __expf(A4[q] + er * cB4[q]) * rde[sc4[q]];
        }
    }
    short* pr = PaggB + (size_t)n * NE + c0;
#pragma unroll
    for (int q = 0; q < 4; q++)
        pr[t + q * 256] = f2bf(acc[q]);
}

// ---------------- head: sum 8 agg partials + LN + FFN + LN ----------------
__global__ __launch_bounds__(128) void k_head(
    const float* __restrict__ aggP, const int* __restrict__ segStartT,
    const int* __restrict__ nsegp,
    const float* __restrict__ cvec, const float* __restrict__ ol_b,
    const float* __restrict__ ln_g, const float* __restrict__ ln_b,
    const float* __restrict__ f1_w, const float* __restrict__ f1_b,
    const float* __restrict__ f2_w, const float* __restrict__ f2_b,
    const float* __restrict__ f3_w, const float* __restrict__ f3_b,
    float* __restrict__ out)
{
    __shared__ float x[H];
    __shared__ float red[H];
    int t = threadIdx.x, row = blockIdx.x;
    int cnt = segStartT[row + 1] - segStartT[row];
    float v = (float)cnt * (ol_b[t] + (float)nsegp[0] * cvec[t]);
    const float* ap = aggP + (size_t)row * H + t;
#pragma unroll
    for (int z = 0; z < 8; z++) v += ap[(size_t)z * N_NODES * H];
    red[t] = v; __syncthreads();
    for (int s = 64; s > 0; s >>= 1) { if (t < s) red[t] += red[t + s]; __syncthreads(); }
    float mu = red[0] * (1.0f / H); __syncthreads();
    float dv = v - mu;
    red[t] = dv * dv; __syncthreads();
    for (int s = 64; s > 0; s >>= 1) { if (t < s) red[t] += red[t + s]; __syncthreads(); }
    float var = red[0] * (1.0f / H); __syncthreads();
    x[t] = dv * rsqrtf(var + 1e-5f) * ln_g[t] + ln_b[t];
    __syncthreads();
    const float* Ws[3] = { f1_w, f2_w, f3_w };
    const float* Bb[3] = { f1_b, f2_b, f3_b };
    for (int l = 0; l < 3; l++) {
        float acc = Bb[l][t];
        const float* Wl = Ws[l];
        for (int k = 0; k < H; k++) acc = fmaf(x[k], Wl[k * H + t], acc);
        float o = fmaxf(acc, 0.0f) + log1pf(expf(-fabsf(acc)));
        __syncthreads();
        x[t] = o;
        __syncthreads();
    }
    float xv = x[t];
    red[t] = xv; __syncthreads();
    for (int s = 64; s > 0; s >>= 1) { if (t < s) red[t] += red[t + s]; __syncthreads(); }
    mu = red[0] * (1.0f / H); __syncthreads();
    float dv2 = xv - mu;
    red[t] = dv2 * dv2; __syncthreads();
    for (int s = 64; s > 0; s >>= 1) { if (t < s) red[t] += red[t + s]; __syncthreads(); }
    var = red[0] * (1.0f / H);
    out[row * H + t] = dv2 * rsqrtf(var + 1e-5f) * ln_g[t] + ln_b[t];
}

// ---------------- launch ----------------

extern "C" void kernel_launch(void* const* d_in, const int* in_sizes, int n_in,
                              void* d_out, int out_size, void* d_ws, size_t ws_size,
                              hipStream_t stream) {
    const float* atom_embs   = (const float*)d_in[0];
    const float* pos         = (const float*)d_in[1];
    const float* edge_weight = (const float*)d_in[2];
    const int*   edge_idx    = (const int*)d_in[3];
    const float* Wq   = (const float*)d_in[4];
    const float* Wk   = (const float*)d_in[5];
    const float* Wv   = (const float*)d_in[6];
    const float* li_w = (const float*)d_in[7];
    const float* li_b = (const float*)d_in[8];
    const float* lj_w = (const float*)d_in[9];
    const float* lj_b = (const float*)d_in[10];
    const float* el_w = (const float*)d_in[11];
    const float* el_b = (const float*)d_in[12];
    const float* rl_w = (const float*)d_in[13];
    const float* rl_b = (const float*)d_in[14];
    const float* ol_w = (const float*)d_in[15];
    const float* ol_b = (const float*)d_in[16];
    const float* ln_g = (const float*)d_in[17];
    const float* ln_b = (const float*)d_in[18];
    const float* f1_w = (const float*)d_in[19];
    const float* f1_b = (const float*)d_in[20];
    const float* f2_w = (const float*)d_in[21];
    const float* f2_b = (const float*)d_in[22];
    const float* f3_w = (const float*)d_in[23];
    const float* f3_b = (const float*)d_in[24];
    float* out = (float*)d_out;

    char* w = (char*)d_ws;
    size_t off = 0;
    auto alloc = [&](size_t bytes) -> void* {
        void* p = w + off;
        off += (bytes + 255) & ~(size_t)255;
        return p;
    };
    int*   src       = (int*)alloc(NE * 4);
    int*   tgt       = (int*)alloc(NE * 4);
    int*   srcS      = (int*)alloc(NE * 4);
    int*   tgtS      = (int*)alloc(NE * 4);
    float* ewS       = (float*)alloc(NE * 4);
    int*   segStart  = (int*)alloc((N_NODES + 1) * 4);
    int*   segStartT = (int*)alloc((N_NODES + 1) * 4);
    int*   cursorS   = (int*)alloc(N_NODES * 4);
    int*   cursorT   = (int*)alloc(N_NODES * 4);
    int*   idxT      = (int*)alloc(NE * 4);
    int*   nsegp     = (int*)alloc(4);
    short* Acat   = (short*)alloc((size_t)NE * KCAT * 2);
    short* ajB    = (short*)alloc((size_t)NE * H * 2);
    short* BcatT  = (short*)alloc((size_t)640 * HH * 2);
    short* WqB    = (short*)alloc((size_t)H * HH * 2);
    short* WkB    = (short*)alloc((size_t)H * HH * 2);
    short* olT    = (short*)alloc((size_t)H * HH * 2);
    short* liT    = (short*)alloc((size_t)H * H * 2);
    short* ljT    = (short*)alloc((size_t)H * H * 2);
    short* embB   = (short*)alloc((size_t)N_NODES * H * 2);
    float* cvec   = (float*)alloc(H * 4);
    short* W2T    = (short*)alloc((size_t)H * 640 * 2);
    short* MT     = (short*)alloc((size_t)H * H * 2);
    short* Y      = (short*)alloc((size_t)N_NODES * H * 2);
    float* Z      = (float*)alloc((size_t)N_NODES * N_NODES * 4);
    float* pv     = (float*)alloc(N_NODES * 4);
    float* colP   = (float*)alloc(NE * 4);
    float* colB   = (float*)alloc(NE * 4);
    short* GT     = (short*)alloc((size_t)H * NE * 2);
    float* rDen   = (float*)alloc((size_t)NE * N_NODES * 4);
    short* PaggB  = (short*)alloc((size_t)N_NODES * NE * 2);
    float* aggP   = (float*)alloc((size_t)8 * N_NODES * H * 4);

    k_scan<<<1, 512, 0, stream>>>(edge_idx, src, tgt, segStart, segStartT,
                                  cursorS, cursorT, nsegp, cvec);
    k_scatter<<<NE / 256, 256, 0, stream>>>(src, tgt, edge_weight, cursorS, cursorT,
                                            srcS, tgtS, ewS, idxT);
    k_prep_all<<<(RTOT + 255) / 256, 256, 0, stream>>>(
        atom_embs, pos, srcS, tgtS, ewS,
        Wq, Wk, Wv, li_w, lj_w, el_w, rl_w, ol_w, el_b, rl_b,
        Acat, ajB, BcatT, WqB, WkB, olT, liT, ljT, embB, cvec);
    k_edgefeat<<<NE / 128, 256, 0, stream>>>(Acat, ajB, liT, ljT, li_b, lj_b, Acat);

    k_smallgemms<<<6, 256, 0, stream>>>(olT, BcatT, WqB, WkB, W2T, MT);
    k_midgemms<<<36, 256, 0, stream>>>(Acat, W2T, MT, embB, GT, Y);
    k_zgemm<<<17, 256, 0, stream>>>(Y, embB, MT, tgtS, ewS, Z, pv, colP, colB);

    k_denom<<<NE, 512, 0, stream>>>(Z, pv, colP, colB, tgtS, ewS, segStart, rDen);
    {
        dim3 g(4, N_NODES);
        k_pagg2<<<g, 256, 0, stream>>>(Z, pv, colP, colB, rDen, tgtS, ewS, srcS,
                                       segStartT, idxT, PaggB);
    }
    // agg = Pagg @ G : [512 x 128] f32, K=4096 split-K=8 -> aggP partials
    {
        dim3 g(1, N_NODES / 128, 8);
        k_gemm<<<g, 256, 0, stream>>>(PaggB, NE, GT, NE, aggP, H, NE, 1.0f, nullptr,
                                      (long)N_NODES * H, 0);
    }
    k_head<<<N_NODES, 128, 0, stream>>>(aggP, segStartT, nsegp, cvec, ol_b,
                                        ln_g, ln_b, f1_w, f1_b, f2_w, f2_b, f3_w, f3_b, out);
}